// Round 7
// baseline (929.689 us; speedup 1.0000x reference)
//
#include <hip/hip_runtime.h>
#include <hip/hip_fp16.h>

#define N_NODES 100000
#define N_EDGES 1200000
#define D 64
#define N_CLASSES 16
#define NG8  (N_NODES / 8)         // half-wave groups (final kernel)
#define NG16 (N_NODES / 16)        // quarter-wave groups (gin layers), 6250
#define GIN_GRID 2048
#define NXCD 8
#define DRANGE ((N_NODES + NXCD - 1) / NXCD)   // 12500
#define ESRC_CAP 1900032           // >= sum(ceil(deg/8)*8) <= E + 7N = 1.9M
#define SENTINEL N_NODES           // index of the all-zero h row

// ======================= CSR build kernels ================================

__global__ void hist_kernel(const int* __restrict__ dst, int* __restrict__ cnt) {
    int e = (blockIdx.x * 256 + threadIdx.x) * 4;
    if (e + 4 <= N_EDGES) {
        int4 d4 = *(const int4*)(dst + e);
        atomicAdd(&cnt[d4.x], 1); atomicAdd(&cnt[d4.y], 1);
        atomicAdd(&cnt[d4.z], 1); atomicAdd(&cnt[d4.w], 1);
    } else {
        for (int k = e; k < N_EDGES; ++k) atomicAdd(&cnt[dst[k]], 1);
    }
}

// Exclusive scan over PADDED degrees: pad_deg = ceil(deg/8)*8.
__global__ void scan_block_kernel(const int* __restrict__ cnt,
                                  int* __restrict__ ofs,
                                  int* __restrict__ partial) {
    __shared__ int s[256];
    int tid = threadIdx.x;
    int i = blockIdx.x * 256 + tid;
    int v = (i < N_NODES) ? ((cnt[i] + 7) & ~7) : 0;
    s[tid] = v;
    __syncthreads();
    for (int d = 1; d < 256; d <<= 1) {
        int t = (tid >= d) ? s[tid - d] : 0;
        __syncthreads();
        s[tid] += t;
        __syncthreads();
    }
    if (i < N_NODES) ofs[i] = s[tid] - v;
    if (tid == 255) partial[blockIdx.x] = s[255];
}

__global__ void scan_partials_kernel(int* __restrict__ partial, int nb) {
    __shared__ int s[512];
    int tid = threadIdx.x;
    int v = (tid < nb) ? partial[tid] : 0;
    s[tid] = v;
    __syncthreads();
    for (int d = 1; d < 512; d <<= 1) {
        int t = (tid >= d) ? s[tid - d] : 0;
        __syncthreads();
        s[tid] += t;
        __syncthreads();
    }
    if (tid < nb) partial[tid] = s[tid] - v;
}

__global__ void scan_add_kernel(int* __restrict__ ofs,
                                const int* __restrict__ partial,
                                const int* __restrict__ cnt) {
    int i = blockIdx.x * 256 + threadIdx.x;
    if (i < N_NODES) ofs[i] += partial[blockIdx.x];
    if (i == N_NODES - 1) ofs[N_NODES] = ofs[i] + ((cnt[i] + 7) & ~7);
}

// Pre-fill padded esrc with the sentinel (points at the zero row).
__global__ void fill_sentinel_kernel(int* __restrict__ esrc) {
    int i = blockIdx.x * 256 + threadIdx.x;   // int4 index
    if (i < ESRC_CAP / 4)
        ((int4*)esrc)[i] = make_int4(SENTINEL, SENTINEL, SENTINEL, SENTINEL);
}

// XCD-range-partitioned scatter: each XCD writes only its own dst range ->
// private-L2-resident esrc slice. Real edges land at the FRONT of each
// padded segment (down-cursor), sentinel padding stays at the back.
__global__ __launch_bounds__(256) void scatter_edges_kernel(
        const int* __restrict__ src,
        const int* __restrict__ dst,
        const int* __restrict__ ofs,
        int* __restrict__ cnt,
        int* __restrict__ esrc) {
    int g = blockIdx.x & (NXCD - 1);
    int lo = g * DRANGE, hi = lo + DRANGE;
    int t = (blockIdx.x >> 3) * 256 + threadIdx.x;
    const int NCH = N_EDGES / 4;
    const int STRIDE = (2048 / NXCD) * 256;
    for (int c = t; c < NCH; c += STRIDE) {
        int4 s4 = ((const int4*)src)[c];
        int4 d4 = ((const int4*)dst)[c];
        if (d4.x >= lo && d4.x < hi) esrc[ofs[d4.x] + atomicSub(&cnt[d4.x], 1) - 1] = s4.x;
        if (d4.y >= lo && d4.y < hi) esrc[ofs[d4.y] + atomicSub(&cnt[d4.y], 1) - 1] = s4.y;
        if (d4.z >= lo && d4.z < hi) esrc[ofs[d4.z] + atomicSub(&cnt[d4.z], 1) - 1] = s4.z;
        if (d4.w >= lo && d4.w < hi) esrc[ofs[d4.w] + atomicSub(&cnt[d4.w], 1) - 1] = s4.w;
    }
}

// ================= f32 -> f16 convert (layer-0 input) =====================
__global__ void cvt_f32_f16_kernel(const float* __restrict__ in, __half* __restrict__ out) {
    const int N4 = N_NODES * D / 4;
    int i = blockIdx.x * 256 + threadIdx.x;
    if (i < N4) {
        float4 v = ((const float4*)in)[i];
        ((__half2*)out)[2 * i + 0] = __floats2half2_rn(v.x, v.y);
        ((__half2*)out)[2 * i + 1] = __floats2half2_rn(v.z, v.w);
    }
}

// Zero row SENTINEL of the three fp16 h buffers (ws is poisoned once).
__global__ void init_zero_rows_kernel(__half* a, __half* b, __half* c) {
    int tid = threadIdx.x;             // 96 threads
    if (tid < 96) {
        __half* p = (tid < 32) ? a : (tid < 64) ? b : c;
        ((unsigned int*)(p + (size_t)SENTINEL * D))[tid & 31] = 0u;
    }
}

// ============ Fused GIN layer: gather-sum + MLP + relu (fp16 h) ===========
// Quarter-wave layout: 16 lanes per node, lane owns 4 channels (uint2).
// Padded segments (multiple of 8, sentinel -> zero row): no tail, no
// predication. esrc indices: 1 lane-distributed load + 8 shfl broadcasts.
__global__ __launch_bounds__(256, 6) void gin_layer_kernel(
        const __half* __restrict__ h_in,
        const int* __restrict__ ofs,
        const int* __restrict__ esrc,
        const float* __restrict__ W,
        __half* __restrict__ h_out) {
    __shared__ float Ws[D][D];                       // [in][out], 16KB
    __shared__ __align__(16) float vs[4][4][68];     // +4 pad
    int tid = threadIdx.x;
    for (int k = tid; k < D * D; k += 256)
        Ws[k >> 6][k & 63] = W[k];
    __syncthreads();   // the only barrier
    int w = tid >> 6;
    int lane = tid & 63;
    int q = lane >> 4;         // node within group of 4
    int c4 = lane & 15;        // uint2 slot: channels 4*c4 .. 4*c4+3
    const uint2* hp = (const uint2*)h_in;  // row = 16 uint2

    for (int g = blockIdx.x; g < NG16; g += GIN_GRID) {
        int n = g * 16 + w * 4 + q;
        uint2 self = hp[(size_t)n * 16 + c4];
        float2 sl = __half22float2(*(const __half2*)&self.x);
        float2 sh = __half22float2(*(const __half2*)&self.y);
        float a0 = sl.x, a1 = sl.y, a2 = sh.x, a3 = sh.y;

        int k = ofs[n], end = ofs[n + 1];
        for (; k < end; k += 8) {
            int e = esrc[k + (c4 & 7)];          // one load serves 8 indices
            int s0 = __shfl(e, 0, 16), s1 = __shfl(e, 1, 16);
            int s2 = __shfl(e, 2, 16), s3 = __shfl(e, 3, 16);
            int s4 = __shfl(e, 4, 16), s5 = __shfl(e, 5, 16);
            int s6 = __shfl(e, 6, 16), s7 = __shfl(e, 7, 16);
            uint2 r0 = hp[(size_t)s0 * 16 + c4];
            uint2 r1 = hp[(size_t)s1 * 16 + c4];
            uint2 r2 = hp[(size_t)s2 * 16 + c4];
            uint2 r3 = hp[(size_t)s3 * 16 + c4];
            uint2 r4 = hp[(size_t)s4 * 16 + c4];
            uint2 r5 = hp[(size_t)s5 * 16 + c4];
            uint2 r6 = hp[(size_t)s6 * 16 + c4];
            uint2 r7 = hp[(size_t)s7 * 16 + c4];
#define ACC(R) { float2 lo = __half22float2(*(const __half2*)&R.x); \
                 float2 hi = __half22float2(*(const __half2*)&R.y); \
                 a0 += lo.x; a1 += lo.y; a2 += hi.x; a3 += hi.y; }
            ACC(r0) ACC(r1) ACC(r2) ACC(r3) ACC(r4) ACC(r5) ACC(r6) ACC(r7)
#undef ACC
        }

        *(float4*)&vs[w][q][4 * c4] = make_float4(a0, a1, a2, a3);
        // wave-local LDS RAW: ordered by lgkmcnt, no barrier
        float o0 = 0.f, o1 = 0.f, o2 = 0.f, o3 = 0.f;
#pragma unroll
        for (int i = 0; i < D; ++i) {
            float vi = vs[w][q][i];                       // broadcast within quarter
            float4 wr = *(const float4*)&Ws[i][4 * c4];   // 2 lanes/bank: free
            o0 = fmaf(vi, wr.x, o0); o1 = fmaf(vi, wr.y, o1);
            o2 = fmaf(vi, wr.z, o2); o3 = fmaf(vi, wr.w, o3);
        }
        uint2 ov;
        *(__half2*)&ov.x = __floats2half2_rn(fmaxf(o0, 0.f), fmaxf(o1, 0.f));
        *(__half2*)&ov.y = __floats2half2_rn(fmaxf(o2, 0.f), fmaxf(o3, 0.f));
        ((uint2*)h_out)[(size_t)n * 16 + c4] = ov;
    }
}

// ============ Final: L2-normalize + 64->16 linear (fp16 in) ===============
__global__ __launch_bounds__(256) void final_kernel(
        const __half* __restrict__ h,
        const float* __restrict__ W_out,
        const float* __restrict__ b_out,
        float* __restrict__ out,    // [N,16]
        float* __restrict__ feat) { // [N,64]
    __shared__ float Wo[D][N_CLASSES];
    __shared__ float fs[4][2][D];
    int tid = threadIdx.x;
    for (int k = tid; k < D * N_CLASSES; k += 256)
        Wo[k >> 4][k & 15] = W_out[k];
    __syncthreads();
    int w = tid >> 6;
    int lane = tid & 63;
    int hh = lane >> 5;
    int c2 = lane & 31;
    const __half2* hp = (const __half2*)h;
    float bias = b_out[lane & 15];

    for (int g = blockIdx.x; g < NG8; g += GIN_GRID) {
        int n = g * 8 + w * 2 + hh;
        float2 v = __half22float2(hp[(size_t)n * 32 + c2]);
        float ss = v.x * v.x + v.y * v.y;
#pragma unroll
        for (int off = 16; off; off >>= 1)   // stays within half-wave
            ss += __shfl_xor(ss, off);
        float rinv = 1.f / fmaxf(sqrtf(ss), 1e-12f);
        float f0 = v.x * rinv, f1 = v.y * rinv;
        ((float2*)feat)[(size_t)n * 32 + c2] = make_float2(f0, f1);
        fs[w][hh][2 * c2 + 0] = f0;
        fs[w][hh][2 * c2 + 1] = f1;
        // wave-local LDS RAW: no barrier
        if (c2 < N_CLASSES) {
            float acc = bias;
#pragma unroll
            for (int i = 0; i < D; ++i)
                acc = fmaf(fs[w][hh][i], Wo[i][c2], acc);
            out[(size_t)n * N_CLASSES + c2] = acc;
        }
    }
}

// ==========================================================================
extern "C" void kernel_launch(void* const* d_in, const int* in_sizes, int n_in,
                              void* d_out, int out_size, void* d_ws, size_t ws_size,
                              hipStream_t stream) {
    const float* x     = (const float*)d_in[0];
    const int*   src   = (const int*)d_in[1];
    const int*   dst   = (const int*)d_in[2];
    const float* W0    = (const float*)d_in[3];
    const float* W1    = (const float*)d_in[4];
    const float* W2    = (const float*)d_in[5];
    const float* W_out = (const float*)d_in[6];
    const float* b_out = (const float*)d_in[7];

    float* out  = (float*)d_out;                                  // [N,16]
    float* feat = (float*)d_out + (size_t)N_NODES * N_CLASSES;    // [N,64]

    const int NB_NODE  = (N_NODES + 255) / 256;       // 391
    const int NB_EDGE4 = (N_EDGES / 4 + 255) / 256;   // 1172
    const int NB_CVT   = (N_NODES * D / 4 + 255) / 256;
    const int NB_FILL  = (ESRC_CAP / 4 + 255) / 256;

    // ws layout (256B-aligned slabs); h buffers have N_NODES+1 rows (zero row)
    size_t off = 0;
    auto alloc = [&](size_t bytes) { size_t o = off; off = (off + bytes + 255) & ~(size_t)255; return o; };
    size_t o_cnt     = alloc((size_t)N_NODES * 4);
    size_t o_partial = alloc(512 * 4);
    size_t o_ofs     = alloc(((size_t)N_NODES + 1) * 4);
    size_t o_esrc    = alloc((size_t)ESRC_CAP * 4);
    size_t o_x16     = alloc((size_t)(N_NODES + 1) * D * 2);
    size_t o_bufA    = alloc((size_t)(N_NODES + 1) * D * 2);
    size_t o_bufB    = alloc((size_t)(N_NODES + 1) * D * 2);

    char* w8 = (char*)d_ws;
    int*    cnt     = (int*)(w8 + o_cnt);
    int*    partial = (int*)(w8 + o_partial);
    int*    ofs     = (int*)(w8 + o_ofs);
    int*    esrc    = (int*)(w8 + o_esrc);
    __half* x16     = (__half*)(w8 + o_x16);
    __half* bufA    = (__half*)(w8 + o_bufA);
    __half* bufB    = (__half*)(w8 + o_bufB);

    // --- padded CSR build (once, reused by 3 layers) ---
    hipMemsetAsync(cnt, 0, (size_t)N_NODES * 4, stream);
    fill_sentinel_kernel<<<NB_FILL, 256, 0, stream>>>(esrc);
    hist_kernel<<<NB_EDGE4, 256, 0, stream>>>(dst, cnt);
    scan_block_kernel<<<NB_NODE, 256, 0, stream>>>(cnt, ofs, partial);
    scan_partials_kernel<<<1, 512, 0, stream>>>(partial, NB_NODE);
    scan_add_kernel<<<NB_NODE, 256, 0, stream>>>(ofs, partial, cnt);
    scatter_edges_kernel<<<2048, 256, 0, stream>>>(src, dst, ofs, cnt, esrc);

    // --- x -> fp16; zero rows for sentinel ---
    cvt_f32_f16_kernel<<<NB_CVT, 256, 0, stream>>>(x, x16);
    init_zero_rows_kernel<<<1, 96, 0, stream>>>(x16, bufA, bufB);

    // --- 3 fused GIN layers, then final ---
    gin_layer_kernel<<<GIN_GRID, 256, 0, stream>>>(x16,  ofs, esrc, W0, bufA);
    gin_layer_kernel<<<GIN_GRID, 256, 0, stream>>>(bufA, ofs, esrc, W1, bufB);
    gin_layer_kernel<<<GIN_GRID, 256, 0, stream>>>(bufB, ofs, esrc, W2, bufA);
    final_kernel<<<GIN_GRID, 256, 0, stream>>>(bufA, W_out, b_out, out, feat);
}

// Round 8
// 321.577 us; speedup vs baseline: 2.8910x; 2.8910x over previous
//
#include <hip/hip_runtime.h>
#include <hip/hip_fp16.h>

#define N_NODES 100000
#define N_EDGES 1200000
#define D 64
#define N_CLASSES 16
#define NG8  (N_NODES / 8)         // half-wave groups (final kernel)
#define NG16 (N_NODES / 16)        // quarter-wave groups (gin layers), 6250
#define GIN_GRID 2048
#define NXCD 8
#define DRANGE ((N_NODES + NXCD - 1) / NXCD)   // 12500
#define ESRC_CAP 1900032           // >= sum(ceil(deg/8)*8) <= E + 7N
#define SENTINEL N_NODES           // index of the all-zero h row

// ======================= CSR build kernels ================================

__global__ void hist_kernel(const int* __restrict__ dst, int* __restrict__ cnt) {
    int e = (blockIdx.x * 256 + threadIdx.x) * 4;
    if (e + 4 <= N_EDGES) {
        int4 d4 = *(const int4*)(dst + e);
        atomicAdd(&cnt[d4.x], 1); atomicAdd(&cnt[d4.y], 1);
        atomicAdd(&cnt[d4.z], 1); atomicAdd(&cnt[d4.w], 1);
    } else {
        for (int k = e; k < N_EDGES; ++k) atomicAdd(&cnt[dst[k]], 1);
    }
}

// Exclusive scan over PADDED degrees: pad_deg = ceil(deg/8)*8.
__global__ void scan_block_kernel(const int* __restrict__ cnt,
                                  int* __restrict__ ofs,
                                  int* __restrict__ partial) {
    __shared__ int s[256];
    int tid = threadIdx.x;
    int i = blockIdx.x * 256 + tid;
    int v = (i < N_NODES) ? ((cnt[i] + 7) & ~7) : 0;
    s[tid] = v;
    __syncthreads();
    for (int d = 1; d < 256; d <<= 1) {
        int t = (tid >= d) ? s[tid - d] : 0;
        __syncthreads();
        s[tid] += t;
        __syncthreads();
    }
    if (i < N_NODES) ofs[i] = s[tid] - v;
    if (tid == 255) partial[blockIdx.x] = s[255];
}

__global__ void scan_partials_kernel(int* __restrict__ partial, int nb) {
    __shared__ int s[512];
    int tid = threadIdx.x;
    int v = (tid < nb) ? partial[tid] : 0;
    s[tid] = v;
    __syncthreads();
    for (int d = 1; d < 512; d <<= 1) {
        int t = (tid >= d) ? s[tid - d] : 0;
        __syncthreads();
        s[tid] += t;
        __syncthreads();
    }
    if (tid < nb) partial[tid] = s[tid] - v;
}

__global__ void scan_add_kernel(int* __restrict__ ofs,
                                const int* __restrict__ partial,
                                const int* __restrict__ cnt) {
    int i = blockIdx.x * 256 + threadIdx.x;
    if (i < N_NODES) ofs[i] += partial[blockIdx.x];
    if (i == N_NODES - 1) ofs[N_NODES] = ofs[i] + ((cnt[i] + 7) & ~7);
}

// Pre-fill padded esrc with the sentinel (points at the zero row).
__global__ void fill_sentinel_kernel(int* __restrict__ esrc) {
    int i = blockIdx.x * 256 + threadIdx.x;   // int4 index
    if (i < ESRC_CAP / 4)
        ((int4*)esrc)[i] = make_int4(SENTINEL, SENTINEL, SENTINEL, SENTINEL);
}

// XCD-range-partitioned scatter: each XCD writes only its own dst range ->
// private-L2-resident esrc slice. Real edges land at the FRONT of each
// padded segment (down-cursor), sentinel padding stays at the back.
__global__ __launch_bounds__(256) void scatter_edges_kernel(
        const int* __restrict__ src,
        const int* __restrict__ dst,
        const int* __restrict__ ofs,
        int* __restrict__ cnt,
        int* __restrict__ esrc) {
    int g = blockIdx.x & (NXCD - 1);
    int lo = g * DRANGE, hi = lo + DRANGE;
    int t = (blockIdx.x >> 3) * 256 + threadIdx.x;
    const int NCH = N_EDGES / 4;
    const int STRIDE = (2048 / NXCD) * 256;
    for (int c = t; c < NCH; c += STRIDE) {
        int4 s4 = ((const int4*)src)[c];
        int4 d4 = ((const int4*)dst)[c];
        if (d4.x >= lo && d4.x < hi) esrc[ofs[d4.x] + atomicSub(&cnt[d4.x], 1) - 1] = s4.x;
        if (d4.y >= lo && d4.y < hi) esrc[ofs[d4.y] + atomicSub(&cnt[d4.y], 1) - 1] = s4.y;
        if (d4.z >= lo && d4.z < hi) esrc[ofs[d4.z] + atomicSub(&cnt[d4.z], 1) - 1] = s4.z;
        if (d4.w >= lo && d4.w < hi) esrc[ofs[d4.w] + atomicSub(&cnt[d4.w], 1) - 1] = s4.w;
    }
}

// ================= f32 -> f16 convert (layer-0 input) =====================
__global__ void cvt_f32_f16_kernel(const float* __restrict__ in, __half* __restrict__ out) {
    const int N4 = N_NODES * D / 4;
    int i = blockIdx.x * 256 + threadIdx.x;
    if (i < N4) {
        float4 v = ((const float4*)in)[i];
        ((__half2*)out)[2 * i + 0] = __floats2half2_rn(v.x, v.y);
        ((__half2*)out)[2 * i + 1] = __floats2half2_rn(v.z, v.w);
    }
}

// Zero row SENTINEL of the three fp16 h buffers.
__global__ void init_zero_rows_kernel(__half* a, __half* b, __half* c) {
    int tid = threadIdx.x;             // 96 threads
    if (tid < 96) {
        __half* p = (tid < 32) ? a : (tid < 64) ? b : c;
        ((unsigned int*)(p + (size_t)SENTINEL * D))[tid & 31] = 0u;
    }
}

// ============ Fused GIN layer: gather-sum + MLP + relu (fp16 h) ===========
// Quarter-wave layout: 16 lanes per node, lane owns 4 channels (uint2 = 8B).
// Padded segments (multiple of 8, sentinel -> zero row): no tail, no
// predication, no clamp. Indices: 2 aligned int4 loads (same addr across the
// 16-lane group -> broadcast transaction). 8 row-gathers in flight.
__global__ __launch_bounds__(256) void gin_layer_kernel(
        const __half* __restrict__ h_in,
        const int* __restrict__ ofs,
        const int* __restrict__ esrc,
        const float* __restrict__ W,
        __half* __restrict__ h_out) {
    __shared__ float Ws[D][D];                       // [in][out], 16KB
    __shared__ __align__(16) float vs[4][4][68];     // +4 pad
    int tid = threadIdx.x;
    for (int k = tid; k < D * D; k += 256)
        Ws[k >> 6][k & 63] = W[k];
    __syncthreads();   // the only barrier
    int w = tid >> 6;
    int lane = tid & 63;
    int q = lane >> 4;         // node within group of 4
    int c4 = lane & 15;        // uint2 slot: channels 4*c4 .. 4*c4+3
    const uint2* hp = (const uint2*)h_in;  // row = 16 uint2

    for (int g = blockIdx.x; g < NG16; g += GIN_GRID) {
        int n = g * 16 + w * 4 + q;
        uint2 self = hp[(size_t)n * 16 + c4];
        float2 sl = __half22float2(*(const __half2*)&self.x);
        float2 sh = __half22float2(*(const __half2*)&self.y);
        float a0 = sl.x, a1 = sl.y, a2 = sh.x, a3 = sh.y;

        int k = ofs[n], end = ofs[n + 1];
        for (; k < end; k += 8) {
            int4 i0 = *(const int4*)(esrc + k);       // 8-aligned: ok
            int4 i1 = *(const int4*)(esrc + k + 4);
            uint2 r0 = hp[(size_t)i0.x * 16 + c4];
            uint2 r1 = hp[(size_t)i0.y * 16 + c4];
            uint2 r2 = hp[(size_t)i0.z * 16 + c4];
            uint2 r3 = hp[(size_t)i0.w * 16 + c4];
            uint2 r4 = hp[(size_t)i1.x * 16 + c4];
            uint2 r5 = hp[(size_t)i1.y * 16 + c4];
            uint2 r6 = hp[(size_t)i1.z * 16 + c4];
            uint2 r7 = hp[(size_t)i1.w * 16 + c4];
#define ACC(R) { float2 lo = __half22float2(*(const __half2*)&R.x); \
                 float2 hi = __half22float2(*(const __half2*)&R.y); \
                 a0 += lo.x; a1 += lo.y; a2 += hi.x; a3 += hi.y; }
            ACC(r0) ACC(r1) ACC(r2) ACC(r3) ACC(r4) ACC(r5) ACC(r6) ACC(r7)
#undef ACC
        }

        *(float4*)&vs[w][q][4 * c4] = make_float4(a0, a1, a2, a3);
        // wave-local LDS RAW: ordered by lgkmcnt, no barrier
        float o0 = 0.f, o1 = 0.f, o2 = 0.f, o3 = 0.f;
#pragma unroll
        for (int i = 0; i < D; ++i) {
            float vi = vs[w][q][i];                       // broadcast within quarter
            float4 wr = *(const float4*)&Ws[i][4 * c4];   // 2 lanes/bank: free
            o0 = fmaf(vi, wr.x, o0); o1 = fmaf(vi, wr.y, o1);
            o2 = fmaf(vi, wr.z, o2); o3 = fmaf(vi, wr.w, o3);
        }
        uint2 ov;
        *(__half2*)&ov.x = __floats2half2_rn(fmaxf(o0, 0.f), fmaxf(o1, 0.f));
        *(__half2*)&ov.y = __floats2half2_rn(fmaxf(o2, 0.f), fmaxf(o3, 0.f));
        ((uint2*)h_out)[(size_t)n * 16 + c4] = ov;
    }
}

// ============ Final: L2-normalize + 64->16 linear (fp16 in) ===============
__global__ __launch_bounds__(256) void final_kernel(
        const __half* __restrict__ h,
        const float* __restrict__ W_out,
        const float* __restrict__ b_out,
        float* __restrict__ out,    // [N,16]
        float* __restrict__ feat) { // [N,64]
    __shared__ float Wo[D][N_CLASSES];
    __shared__ float fs[4][2][D];
    int tid = threadIdx.x;
    for (int k = tid; k < D * N_CLASSES; k += 256)
        Wo[k >> 4][k & 15] = W_out[k];
    __syncthreads();
    int w = tid >> 6;
    int lane = tid & 63;
    int hh = lane >> 5;
    int c2 = lane & 31;
    const __half2* hp = (const __half2*)h;
    float bias = b_out[lane & 15];

    for (int g = blockIdx.x; g < NG8; g += GIN_GRID) {
        int n = g * 8 + w * 2 + hh;
        float2 v = __half22float2(hp[(size_t)n * 32 + c2]);
        float ss = v.x * v.x + v.y * v.y;
#pragma unroll
        for (int off = 16; off; off >>= 1)   // stays within half-wave
            ss += __shfl_xor(ss, off);
        float rinv = 1.f / fmaxf(sqrtf(ss), 1e-12f);
        float f0 = v.x * rinv, f1 = v.y * rinv;
        ((float2*)feat)[(size_t)n * 32 + c2] = make_float2(f0, f1);
        fs[w][hh][2 * c2 + 0] = f0;
        fs[w][hh][2 * c2 + 1] = f1;
        // wave-local LDS RAW: no barrier
        if (c2 < N_CLASSES) {
            float acc = bias;
#pragma unroll
            for (int i = 0; i < D; ++i)
                acc = fmaf(fs[w][hh][i], Wo[i][c2], acc);
            out[(size_t)n * N_CLASSES + c2] = acc;
        }
    }
}

// ==========================================================================
extern "C" void kernel_launch(void* const* d_in, const int* in_sizes, int n_in,
                              void* d_out, int out_size, void* d_ws, size_t ws_size,
                              hipStream_t stream) {
    const float* x     = (const float*)d_in[0];
    const int*   src   = (const int*)d_in[1];
    const int*   dst   = (const int*)d_in[2];
    const float* W0    = (const float*)d_in[3];
    const float* W1    = (const float*)d_in[4];
    const float* W2    = (const float*)d_in[5];
    const float* W_out = (const float*)d_in[6];
    const float* b_out = (const float*)d_in[7];

    float* out  = (float*)d_out;                                  // [N,16]
    float* feat = (float*)d_out + (size_t)N_NODES * N_CLASSES;    // [N,64]

    const int NB_NODE  = (N_NODES + 255) / 256;       // 391
    const int NB_EDGE4 = (N_EDGES / 4 + 255) / 256;   // 1172
    const int NB_CVT   = (N_NODES * D / 4 + 255) / 256;
    const int NB_FILL  = (ESRC_CAP / 4 + 255) / 256;

    // ws layout (256B-aligned slabs); h buffers have N_NODES+1 rows (zero row)
    size_t off = 0;
    auto alloc = [&](size_t bytes) { size_t o = off; off = (off + bytes + 255) & ~(size_t)255; return o; };
    size_t o_cnt     = alloc((size_t)N_NODES * 4);
    size_t o_partial = alloc(512 * 4);
    size_t o_ofs     = alloc(((size_t)N_NODES + 1) * 4);
    size_t o_esrc    = alloc((size_t)ESRC_CAP * 4);
    size_t o_x16     = alloc((size_t)(N_NODES + 1) * D * 2);
    size_t o_bufA    = alloc((size_t)(N_NODES + 1) * D * 2);
    size_t o_bufB    = alloc((size_t)(N_NODES + 1) * D * 2);

    char* w8 = (char*)d_ws;
    int*    cnt     = (int*)(w8 + o_cnt);
    int*    partial = (int*)(w8 + o_partial);
    int*    ofs     = (int*)(w8 + o_ofs);
    int*    esrc    = (int*)(w8 + o_esrc);
    __half* x16     = (__half*)(w8 + o_x16);
    __half* bufA    = (__half*)(w8 + o_bufA);
    __half* bufB    = (__half*)(w8 + o_bufB);

    // --- padded CSR build (once, reused by 3 layers) ---
    hipMemsetAsync(cnt, 0, (size_t)N_NODES * 4, stream);
    fill_sentinel_kernel<<<NB_FILL, 256, 0, stream>>>(esrc);
    hist_kernel<<<NB_EDGE4, 256, 0, stream>>>(dst, cnt);
    scan_block_kernel<<<NB_NODE, 256, 0, stream>>>(cnt, ofs, partial);
    scan_partials_kernel<<<1, 512, 0, stream>>>(partial, NB_NODE);
    scan_add_kernel<<<NB_NODE, 256, 0, stream>>>(ofs, partial, cnt);
    scatter_edges_kernel<<<2048, 256, 0, stream>>>(src, dst, ofs, cnt, esrc);

    // --- x -> fp16; zero rows for sentinel ---
    cvt_f32_f16_kernel<<<NB_CVT, 256, 0, stream>>>(x, x16);
    init_zero_rows_kernel<<<1, 96, 0, stream>>>(x16, bufA, bufB);

    // --- 3 fused GIN layers, then final ---
    gin_layer_kernel<<<GIN_GRID, 256, 0, stream>>>(x16,  ofs, esrc, W0, bufA);
    gin_layer_kernel<<<GIN_GRID, 256, 0, stream>>>(bufA, ofs, esrc, W1, bufB);
    gin_layer_kernel<<<GIN_GRID, 256, 0, stream>>>(bufB, ofs, esrc, W2, bufA);
    final_kernel<<<GIN_GRID, 256, 0, stream>>>(bufA, W_out, b_out, out, feat);
}